// Round 12
// baseline (390.123 us; speedup 1.0000x reference)
//
#include <hip/hip_runtime.h>
#include <math.h>

typedef unsigned short ushort_t;
typedef __attribute__((ext_vector_type(8))) short bf16x8;
typedef __attribute__((ext_vector_type(4))) float f32x4;

namespace {
constexpr int B = 8, S = 2048, H = 128, NH = 4, HS = 32;
constexpr float EPS = 1e-8f;
constexpr float SCALE = 0.17677669529663687f;  // 1/sqrt(32)
constexpr int QT = 16, KT = 64;
constexpr int NE = B * S * H;  // 2,097,152 elements per tensor
constexpr int NML = B * NH * S;  // per-half (m,l) rows
}

__device__ __forceinline__ ushort_t f2bf(float f) {
  unsigned u = __float_as_uint(f);
  unsigned r = (u + 0x7FFFu + ((u >> 16) & 1u)) >> 16;  // RNE
  return (ushort_t)r;
}

__device__ __forceinline__ float bf2f(ushort_t u) {
  return __uint_as_float((unsigned)u << 16);
}

__device__ __forceinline__ f32x4 mfma16(bf16x8 a, bf16x8 b, f32x4 c) {
  return __builtin_amdgcn_mfma_f32_16x16x32_bf16(a, b, c, 0, 0, 0);
}

// ---------- Kernel 0: transpose+convert weights to bf16 Wt[n][k]; SCALE folded into Wq/Wqb ----
// Also zeroes the mask-nonzero flag (stream order: completes before the scan dispatch starts).
__global__ __launch_bounds__(256) void wcvt_kernel(
    const float* __restrict__ Wq, const float* __restrict__ Wk, const float* __restrict__ Wv,
    const float* __restrict__ Wqb, const float* __restrict__ Wkb, const float* __restrict__ Wf,
    ushort_t* __restrict__ Wt, unsigned* __restrict__ mflag)
{
  if (blockIdx.x == 0 && blockIdx.y == 0 && threadIdx.x == 0) *mflag = 0u;
  const float* Ws[6] = {Wq, Wk, Wv, Wqb, Wkb, Wf};
  const float scl[6] = {SCALE, 1.f, 1.f, SCALE, 1.f, 1.f};
  const int m = blockIdx.y;
  const int kb = blockIdx.x;           // 32-row slab of k
  const float* W = Ws[m];
  const float sc = scl[m];
  __shared__ float T[32 * 132];
  const int t = threadIdx.x;
#pragma unroll
  for (int u = 0; u < 4; ++u) {        // 32 rows x 32 float4
    const int idx = u * 256 + t;
    const int row = idx >> 5, c4 = idx & 31;
    const float4 v = *(const float4*)&W[(kb * 32 + row) * H + c4 * 4];
    *(float4*)&T[row * 132 + c4 * 4] = v;
  }
  __syncthreads();
#pragma unroll
  for (int u = 0; u < 16; ++u) {       // 128 n x 32 kk
    const int idx = u * 256 + t;
    const int n = idx >> 5, kk = idx & 31;
    Wt[m * (H * H) + n * H + kb * 32 + kk] = f2bf(T[kk * 132 + n] * sc);
  }
}

// ---------- Kernel 0b: mask OR-scan (dedicated dispatch: full machine, BW-bound, ~25us) ------
__global__ __launch_bounds__(256) void mscan_kernel(
    const uint4* __restrict__ mask4, unsigned* __restrict__ mflag)
{
  const long n = (long)B * S * S / 4;   // uint4 count
  unsigned acc = 0;
  for (long i = (long)blockIdx.x * 256 + threadIdx.x; i < n; i += (long)1024 * 256) {
    const uint4 v = mask4[i];
    acc |= v.x | v.y | v.z | v.w;
  }
  if (__any(acc != 0) && (threadIdx.x & 63) == 0) atomicOr(mflag, 1u);
}

// ---------- Kernel 1: 5 projections via MFMA; blockIdx.y = projection ----------
// Q,K,Qb,Kb: [B][NH][S][HS] bf16 (Q/Qb pre-scaled) ; V: transposed [B][NH][HS][S] bf16
__global__ __launch_bounds__(256) void proj_kernel(
    const float* __restrict__ item, const float* __restrict__ beh,
    const ushort_t* __restrict__ Wt,
    const float* __restrict__ bq, const float* __restrict__ bk, const float* __restrict__ bv,
    const float* __restrict__ bqb, const float* __restrict__ bkb,
    ushort_t* __restrict__ Qo, ushort_t* __restrict__ Ko, ushort_t* __restrict__ Qbo,
    ushort_t* __restrict__ Kbo, ushort_t* __restrict__ Vto)
{
  __shared__ ushort_t Xs[32 * 136];
  __shared__ ushort_t Yb[32 * 136];
  const int t = threadIdx.x;
  const int p = blockIdx.y;
  const long r0 = (long)blockIdx.x * 32;
  const float* X = (p < 3) ? item : beh;
#pragma unroll
  for (int u = 0; u < 4; ++u) {        // 32 rows x 32 float4
    const int idx = u * 256 + t;
    const int row = idx >> 5, c4 = idx & 31;
    const float4 v = *(const float4*)&X[(r0 + row) * H + c4 * 4];
    unsigned long long pk = (unsigned long long)f2bf(v.x) | ((unsigned long long)f2bf(v.y) << 16)
        | ((unsigned long long)f2bf(v.z) << 32) | ((unsigned long long)f2bf(v.w) << 48);
    *(unsigned long long*)&Xs[row * 136 + c4 * 4] = pk;
  }
  __syncthreads();

  const int w = t >> 6, l = t & 63, l15 = l & 15, quad = l >> 4;
  const int bb = (int)(r0 >> 11);
  const int s0 = (int)(r0 & (S - 1));
  const float* bias[5] = {bq, bk, bv, bqb, bkb};
  const float bscale[5] = {SCALE, 1.f, 1.f, SCALE, 1.f};
  ushort_t* dsts[5] = {Qo, Ko, Vto, Qbo, Kbo};

  bf16x8 af[2][4];
#pragma unroll
  for (int mt = 0; mt < 2; ++mt)
#pragma unroll
    for (int ks = 0; ks < 4; ++ks)
      af[mt][ks] = *(const bf16x8*)&Xs[(mt * 16 + l15) * 136 + ks * 32 + quad * 8];

  f32x4 acc[2][2];
#pragma unroll
  for (int nt = 0; nt < 2; ++nt) {
    const float bcol = bias[p][w * 32 + nt * 16 + l15] * bscale[p];
#pragma unroll
    for (int mt = 0; mt < 2; ++mt)
      acc[mt][nt] = (f32x4){bcol, bcol, bcol, bcol};
  }
  const ushort_t* Wp = Wt + p * (H * H);
#pragma unroll
  for (int ks = 0; ks < 4; ++ks) {
    bf16x8 bfr[2];
#pragma unroll
    for (int nt = 0; nt < 2; ++nt)
      bfr[nt] = *(const bf16x8*)&Wp[(w * 32 + nt * 16 + l15) * H + ks * 32 + quad * 8];
#pragma unroll
    for (int mt = 0; mt < 2; ++mt)
#pragma unroll
      for (int nt = 0; nt < 2; ++nt)
        acc[mt][nt] = mfma16(af[mt][ks], bfr[nt], acc[mt][nt]);
  }
  // repack through LDS: Yb[row][col]
#pragma unroll
  for (int mt = 0; mt < 2; ++mt)
#pragma unroll
    for (int nt = 0; nt < 2; ++nt)
#pragma unroll
      for (int r = 0; r < 4; ++r)
        Yb[(mt * 16 + quad * 4 + r) * 136 + w * 32 + nt * 16 + l15] = f2bf(acc[mt][nt][r]);
  __syncthreads();
  ushort_t* dst = dsts[p];
  if (p == 2) {
    // Vt [b][h][d][s]: thread t -> d = t>>1, 16 consecutive s
    const int d = t >> 1, sh = (t & 1) * 16;
    ushort_t tmp[16];
#pragma unroll
    for (int i = 0; i < 16; ++i) tmp[i] = Yb[(sh + i) * 136 + d];
    const long gidx = ((long)(bb * NH + (d >> 5)) * HS + (d & 31)) * S + s0 + sh;
    *(uint4*)&dst[gidx] = *(const uint4*)&tmp[0];
    *(uint4*)&dst[gidx + 8] = *(const uint4*)&tmp[8];
  } else {
    // [b][h][s][d]: thread t -> row = t>>3, 16 consecutive cols
    const int row = t >> 3, cb = (t & 7) * 16;
    const int h = cb >> 5, dd = cb & 31;
    const long gidx = ((long)(bb * NH + h) * S + s0 + row) * HS + dd;
    *(uint4*)&dst[gidx] = *(const uint4*)&Yb[row * 136 + cb];
    *(uint4*)&dst[gidx + 8] = *(const uint4*)&Yb[row * 136 + cb + 8];
  }
}

// ---------- Kernel 2a: mask-free flash attention, SINGLE-Q, split-K2, 4 blocks/CU ----------
// Runs only when the mask is all-zero (early exit otherwise). r3's single-Q body minus all
// mask machinery: ~100 total regs fits the 4-waves/SIMD bucket at __launch_bounds__(256,4)
// -> 4 blocks/CU = 16 waves/CU, 2x r11's wave count, and the mask stall that sank r3 is gone.
// Grid 2048 blocks 1D; b = bid & 7 gives XCD affinity for K/Kb/V.
__global__ __launch_bounds__(256, 4) void attn_z_kernel(
    const ushort_t* __restrict__ Q, const ushort_t* __restrict__ K,
    const ushort_t* __restrict__ Qb, const ushort_t* __restrict__ Kb,
    const ushort_t* __restrict__ Vt, const unsigned* __restrict__ mflag,
    ushort_t* __restrict__ Op, float* __restrict__ Mp, float* __restrict__ Lp)
{
  if (*mflag != 0u) return;              // mask nonzero -> attn_m handles it
  __shared__ ushort_t Pb[NH][16 * 72];   // per-wave P scratch
  const int t = threadIdx.x;
  const int w = t >> 6;                  // head
  const int l = t & 63, l15 = l & 15, quad = l >> 4, quad4 = quad * 4;
  const int bid = blockIdx.x;
  const int b = bid & 7;                 // XCD-affinity decode
  const int rest = bid >> 3;
  const int q0 = (rest & 127) * QT;
  const int half_ = rest >> 7;
  const long hQ = (long)(b * NH + w) * S * HS;
  const long hV = (long)(b * NH + w) * HS * S;
  const ushort_t* Kp  = K + hQ;
  const ushort_t* Kbp = Kb + hQ;
  const ushort_t* Vp  = Vt + hV;

  // persistent Q/Qb A-fragments (Q pre-scaled by 1/sqrt(HS))
  const bf16x8 qf  = *(const bf16x8*)&Q[hQ + (long)(q0 + l15) * HS + quad * 8];
  const bf16x8 qbf = *(const bf16x8*)&Qb[hQ + (long)(q0 + l15) * HS + quad * 8];

  float mold[4], lsum[4];
  f32x4 O[2];
#pragma unroll
  for (int r = 0; r < 4; ++r) { mold[r] = -1e30f; lsum[r] = 0.f; }
#pragma unroll
  for (int dt = 0; dt < 2; ++dt) O[dt] = (f32x4){0.f, 0.f, 0.f, 0.f};
  ushort_t* Pw = Pb[w];

  const int kt0 = half_ * (S / KT / 2), kt1 = kt0 + (S / KT / 2);
  for (int kt = kt0; kt < kt1; ++kt) {
    const int k0 = kt * KT;
    // K/Kb/V fragment loads (L2/L3-hot; no mask -> zero-init C-operand)
    bf16x8 kf[4], kbf[4], vf[2][2];
#pragma unroll
    for (int nt = 0; nt < 4; ++nt) {
      kf[nt]  = *(const bf16x8*)&Kp[(long)(k0 + nt * 16 + l15) * HS + quad * 8];
      kbf[nt] = *(const bf16x8*)&Kbp[(long)(k0 + nt * 16 + l15) * HS + quad * 8];
    }
#pragma unroll
    for (int dt = 0; dt < 2; ++dt)
#pragma unroll
      for (int ks = 0; ks < 2; ++ks)
        vf[dt][ks] = *(const bf16x8*)&Vp[(long)(dt * 16 + l15) * S + k0 + ks * 32 + quad * 8];
    f32x4 sc[4];
#pragma unroll
    for (int nt = 0; nt < 4; ++nt)
      sc[nt] = (f32x4){0.f, 0.f, 0.f, 0.f};
    // scores = Q'K^T + Qb'Kb^T
#pragma unroll
    for (int nt = 0; nt < 4; ++nt) {
      sc[nt] = mfma16(qbf, kbf[nt], sc[nt]);
      sc[nt] = mfma16(qf, kf[nt], sc[nt]);
    }
    // online softmax in registers
    float alpha[4];
#pragma unroll
    for (int r = 0; r < 4; ++r) {
      float rm = fmaxf(fmaxf(sc[0][r], sc[1][r]), fmaxf(sc[2][r], sc[3][r]));
      rm = fmaxf(rm, __shfl_xor(rm, 1));
      rm = fmaxf(rm, __shfl_xor(rm, 2));
      rm = fmaxf(rm, __shfl_xor(rm, 4));
      rm = fmaxf(rm, __shfl_xor(rm, 8));
      const float mnew = fmaxf(mold[r], rm);
      alpha[r] = __expf(mold[r] - mnew);
      float rs = 0.f;
#pragma unroll
      for (int nt = 0; nt < 4; ++nt) {
        const float p = __expf(sc[nt][r] - mnew);
        sc[nt][r] = p;
        rs += p;
      }
      rs += __shfl_xor(rs, 1);
      rs += __shfl_xor(rs, 2);
      rs += __shfl_xor(rs, 4);
      rs += __shfl_xor(rs, 8);
      lsum[r] = lsum[r] * alpha[r] + rs;
      mold[r] = mnew;
    }
    // rescale O, write P (bf16) to per-wave LDS
#pragma unroll
    for (int dt = 0; dt < 2; ++dt)
#pragma unroll
      for (int r = 0; r < 4; ++r)
        O[dt][r] *= alpha[r];
#pragma unroll
    for (int nt = 0; nt < 4; ++nt)
#pragma unroll
      for (int r = 0; r < 4; ++r)
        Pw[(quad4 + r) * 72 + nt * 16 + l15] = f2bf(sc[nt][r]);
    // P A-frags (intra-wave LDS dependency only) + PV
    bf16x8 pf[2];
#pragma unroll
    for (int ks = 0; ks < 2; ++ks)
      pf[ks] = *(const bf16x8*)&Pw[l15 * 72 + ks * 32 + quad * 8];
#pragma unroll
    for (int dt = 0; dt < 2; ++dt)
#pragma unroll
      for (int ks = 0; ks < 2; ++ks)
        O[dt] = mfma16(pf[ks], vf[dt][ks], O[dt]);
  }
  // epilogue: normalized bf16 partial O + (m,l) per row
#pragma unroll
  for (int r = 0; r < 4; ++r) {
    const float inv = 1.f / lsum[r];
    const long row = (long)b * S + q0 + quad4 + r;
#pragma unroll
    for (int dt = 0; dt < 2; ++dt)
      Op[(long)half_ * NE + row * H + w * 32 + dt * 16 + l15] = f2bf(O[dt][r] * inv);
  }
  if (l15 == 0) {
#pragma unroll
    for (int r = 0; r < 4; ++r) {
      const long idx = ((long)(half_ * B + b) * NH + w) * S + q0 + quad4 + r;
      Mp[idx] = mold[r];
      Lp[idx] = lsum[r];
    }
  }
}

// ---------- Kernel 2b: masked flash attention (exact r8 path), runs only if mask nonzero ----
__global__ __launch_bounds__(256, 2) void attn_m_kernel(
    const ushort_t* __restrict__ Q, const ushort_t* __restrict__ K,
    const ushort_t* __restrict__ Qb, const ushort_t* __restrict__ Kb,
    const ushort_t* __restrict__ Vt, const float* __restrict__ mask,
    const unsigned* __restrict__ mflag,
    ushort_t* __restrict__ Op, float* __restrict__ Mp, float* __restrict__ Lp)
{
  if (*mflag == 0u) return;              // mask all-zero -> attn_z handled it
  __shared__ ushort_t Pb[NH][2][16 * 72];   // per-wave, per-chain P scratch
  const int t = threadIdx.x;
  const int w = t >> 6;                  // head
  const int l = t & 63, l15 = l & 15, quad = l >> 4, quad4 = quad * 4;
  const int q0 = blockIdx.x * 32;        // two 16-row q-tiles
  const int b = blockIdx.y;
  const int half_ = blockIdx.z;
  const long hQ = (long)(b * NH + w) * S * HS;
  const long hV = (long)(b * NH + w) * HS * S;
  const ushort_t* Kp  = K + hQ;
  const ushort_t* Kbp = Kb + hQ;
  const ushort_t* Vp  = Vt + hV;

  bf16x8 qf[2], qbf[2];
#pragma unroll
  for (int c = 0; c < 2; ++c) {
    qf[c]  = *(const bf16x8*)&Q[hQ + (long)(q0 + c * 16 + l15) * HS + quad * 8];
    qbf[c] = *(const bf16x8*)&Qb[hQ + (long)(q0 + c * 16 + l15) * HS + quad * 8];
  }

  const float* mrow[2][4];
#pragma unroll
  for (int c = 0; c < 2; ++c)
#pragma unroll
    for (int r = 0; r < 4; ++r)
      mrow[c][r] = mask + ((long)b * S + q0 + c * 16 + quad4 + r) * S + l15;

  float mold[2][4], lsum[2][4];
  f32x4 O[2][2];
#pragma unroll
  for (int c = 0; c < 2; ++c) {
#pragma unroll
    for (int r = 0; r < 4; ++r) { mold[c][r] = -1e30f; lsum[c][r] = 0.f; }
#pragma unroll
    for (int dt = 0; dt < 2; ++dt) O[c][dt] = (f32x4){0.f, 0.f, 0.f, 0.f};
  }

  const int kt0 = half_ * (S / KT / 2), kt1 = kt0 + (S / KT / 2);

  f32x4 scA[2][4], scB[2][4];
#pragma unroll
  for (int c = 0; c < 2; ++c)
#pragma unroll
    for (int nt = 0; nt < 4; ++nt)
#pragma unroll
      for (int r = 0; r < 4; ++r)
        scA[c][nt][r] = mrow[c][r][kt0 * KT + nt * 16];

  auto body = [&](f32x4 (&sc)[2][4], f32x4 (&scn)[2][4], int k0, int k0n, bool pre) {
    bf16x8 kf[4], kbf[4];
#pragma unroll
    for (int nt = 0; nt < 4; ++nt) {
      kf[nt]  = *(const bf16x8*)&Kp[(long)(k0 + nt * 16 + l15) * HS + quad * 8];
      kbf[nt] = *(const bf16x8*)&Kbp[(long)(k0 + nt * 16 + l15) * HS + quad * 8];
    }
    bf16x8 vf[2][2];
#pragma unroll
    for (int dt = 0; dt < 2; ++dt)
#pragma unroll
      for (int ks = 0; ks < 2; ++ks)
        vf[dt][ks] = *(const bf16x8*)&Vp[(long)(dt * 16 + l15) * S + k0 + ks * 32 + quad * 8];
    if (pre) {
#pragma unroll
      for (int c = 0; c < 2; ++c)
#pragma unroll
        for (int nt = 0; nt < 4; ++nt)
#pragma unroll
          for (int r = 0; r < 4; ++r)
            scn[c][nt][r] = mrow[c][r][k0n + nt * 16];
    }
#pragma unroll
    for (int c = 0; c < 2; ++c)
#pragma unroll
      for (int nt = 0; nt < 4; ++nt) {
        sc[c][nt] = mfma16(qbf[c], kbf[nt], sc[c][nt]);
        sc[c][nt] = mfma16(qf[c], kf[nt], sc[c][nt]);
      }
#pragma unroll
    for (int c = 0; c < 2; ++c) {
      float alpha[4];
#pragma unroll
      for (int r = 0; r < 4; ++r) {
        float rm = fmaxf(fmaxf(sc[c][0][r], sc[c][1][r]), fmaxf(sc[c][2][r], sc[c][3][r]));
        rm = fmaxf(rm, __shfl_xor(rm, 1));
        rm = fmaxf(rm, __shfl_xor(rm, 2));
        rm = fmaxf(rm, __shfl_xor(rm, 4));
        rm = fmaxf(rm, __shfl_xor(rm, 8));
        const float mnew = fmaxf(mold[c][r], rm);
        alpha[r] = __expf(mold[c][r] - mnew);
        float rs = 0.f;
#pragma unroll
        for (int nt = 0; nt < 4; ++nt) {
          const float p = __expf(sc[c][nt][r] - mnew);
          sc[c][nt][r] = p;
          rs += p;
        }
        rs += __shfl_xor(rs, 1);
        rs += __shfl_xor(rs, 2);
        rs += __shfl_xor(rs, 4);
        rs += __shfl_xor(rs, 8);
        lsum[c][r] = lsum[c][r] * alpha[r] + rs;
        mold[c][r] = mnew;
      }
#pragma unroll
      for (int dt = 0; dt < 2; ++dt)
#pragma unroll
        for (int r = 0; r < 4; ++r)
          O[c][dt][r] *= alpha[r];
      ushort_t* Pw = Pb[w][c];
#pragma unroll
      for (int nt = 0; nt < 4; ++nt)
#pragma unroll
        for (int r = 0; r < 4; ++r)
          Pw[(quad4 + r) * 72 + nt * 16 + l15] = f2bf(sc[c][nt][r]);
    }
#pragma unroll
    for (int c = 0; c < 2; ++c) {
      const ushort_t* Pw = Pb[w][c];
      bf16x8 pf[2];
#pragma unroll
      for (int ks = 0; ks < 2; ++ks)
        pf[ks] = *(const bf16x8*)&Pw[l15 * 72 + ks * 32 + quad * 8];
#pragma unroll
      for (int dt = 0; dt < 2; ++dt)
#pragma unroll
        for (int ks = 0; ks < 2; ++ks)
          O[c][dt] = mfma16(pf[ks], vf[dt][ks], O[c][dt]);
    }
  };

  for (int kt = kt0; kt < kt1; kt += 2) {
    body(scA, scB, kt * KT, (kt + 1) * KT, true);
    body(scB, scA, (kt + 1) * KT, (kt + 2) * KT, kt + 2 < kt1);
  }

#pragma unroll
  for (int c = 0; c < 2; ++c) {
#pragma unroll
    for (int r = 0; r < 4; ++r) {
      const float inv = 1.f / lsum[c][r];
      const long row = (long)b * S + q0 + c * 16 + quad4 + r;
#pragma unroll
      for (int dt = 0; dt < 2; ++dt)
        Op[(long)half_ * NE + row * H + w * 32 + dt * 16 + l15] = f2bf(O[c][dt][r] * inv);
    }
    if (l15 == 0) {
#pragma unroll
      for (int r = 0; r < 4; ++r) {
        const long idx = ((long)(half_ * B + b) * NH + w) * S + q0 + c * 16 + quad4 + r;
        Mp[idx] = mold[c][r];
        Lp[idx] = lsum[c][r];
      }
    }
  }
}

// ---------- Kernel 3: merge split-K halves + attn @ Wf + bias + residual + LayerNorm ----------
__global__ __launch_bounds__(256) void out_kernel(
    const ushort_t* __restrict__ Op, const float* __restrict__ Mp, const float* __restrict__ Lp,
    const float* __restrict__ item,
    const ushort_t* __restrict__ Wft, const float* __restrict__ bf_,
    const float* __restrict__ lnw, const float* __restrict__ lnb,
    float* __restrict__ out)
{
  __shared__ ushort_t As[16 * 136];
  __shared__ float Ys[16 * 132];
  const int t = threadIdx.x;
  const long r0 = (long)blockIdx.x * 16;
  {
    // merge halves: 16 rows x 16 chunks of 8 bf16
    const int row = t >> 4, c8 = t & 15;
    const long g = r0 + row;
    const int bb = (int)(g >> 11);
    const int ss = (int)(g & (S - 1));
    const int col0 = c8 * 8;
    const int h = col0 >> 5;
    const long mlidx = ((long)bb * NH + h) * S + ss;
    const float m1 = Mp[mlidx], m2 = Mp[(long)NML + mlidx];
    const float l1 = Lp[mlidx], l2 = Lp[(long)NML + mlidx];
    const float M = fmaxf(m1, m2);
    const float w1 = l1 * __expf(m1 - M), w2 = l2 * __expf(m2 - M);
    const float inv = 1.f / (w1 + w2);
    const float wa = w1 * inv, wb = w2 * inv;
    const uint4 a1 = *(const uint4*)&Op[g * H + col0];
    const uint4 a2 = *(const uint4*)&Op[(long)NE + g * H + col0];
    const ushort_t* p1 = (const ushort_t*)&a1;
    const ushort_t* p2 = (const ushort_t*)&a2;
    ushort_t mg[8];
#pragma unroll
    for (int i = 0; i < 8; ++i)
      mg[i] = f2bf(bf2f(p1[i]) * wa + bf2f(p2[i]) * wb);
    *(uint4*)&As[row * 136 + col0] = *(const uint4*)&mg[0];
  }
  __syncthreads();
  const int w = t >> 6, l = t & 63, l15 = l & 15, quad = l >> 4;
  f32x4 acc[2];
#pragma unroll
  for (int nt = 0; nt < 2; ++nt) {
    const float bcol = bf_[w * 32 + nt * 16 + l15];
    acc[nt] = (f32x4){bcol, bcol, bcol, bcol};
  }
#pragma unroll
  for (int ks = 0; ks < 4; ++ks) {
    const bf16x8 a = *(const bf16x8*)&As[l15 * 136 + ks * 32 + quad * 8];
#pragma unroll
    for (int nt = 0; nt < 2; ++nt) {
      const bf16x8 bfr = *(const bf16x8*)&Wft[(w * 32 + nt * 16 + l15) * H + ks * 32 + quad * 8];
      acc[nt] = mfma16(a, bfr, acc[nt]);
    }
  }
  // Y = acc + item -> LDS
#pragma unroll
  for (int nt = 0; nt < 2; ++nt)
#pragma unroll
    for (int r = 0; r < 4; ++r) {
      const int rl = quad * 4 + r;
      const int col = w * 32 + nt * 16 + l15;
      Ys[rl * 132 + col] = acc[nt][r] + item[(r0 + rl) * H + col];
    }
  __syncthreads();
  // LayerNorm: 16 threads per row, 8 cols each
  const int rl = t >> 4, ch = t & 15;
  float v[8];
#pragma unroll
  for (int g = 0; g < 2; ++g) {
    const float4 y = *(const float4*)&Ys[rl * 132 + ch * 8 + g * 4];
    v[g * 4 + 0] = y.x; v[g * 4 + 1] = y.y; v[g * 4 + 2] = y.z; v[g * 4 + 3] = y.w;
  }
  float s = 0.f;
#pragma unroll
  for (int i = 0; i < 8; ++i) s += v[i];
  s += __shfl_xor(s, 1);
  s += __shfl_xor(s, 2);
  s += __shfl_xor(s, 4);
  s += __shfl_xor(s, 8);
  const float u_ = s * (1.f / H);
  float s2 = 0.f;
#pragma unroll
  for (int i = 0; i < 8; ++i) { const float d = v[i] - u_; s2 += d * d; }
  s2 += __shfl_xor(s2, 1);
  s2 += __shfl_xor(s2, 2);
  s2 += __shfl_xor(s2, 4);
  s2 += __shfl_xor(s2, 8);
  const float rinv = rsqrtf(s2 * (1.f / H) + EPS);
#pragma unroll
  for (int g = 0; g < 2; ++g) {
    float4 o;
    const int col = ch * 8 + g * 4;
    o.x = lnw[col + 0] * ((v[g * 4 + 0] - u_) * rinv) + lnb[col + 0];
    o.y = lnw[col + 1] * ((v[g * 4 + 1] - u_) * rinv) + lnb[col + 1];
    o.z = lnw[col + 2] * ((v[g * 4 + 2] - u_) * rinv) + lnb[col + 2];
    o.w = lnw[col + 3] * ((v[g * 4 + 3] - u_) * rinv) + lnb[col + 3];
    *(float4*)&out[(r0 + rl) * H + col] = o;
  }
}

extern "C" void kernel_launch(void* const* d_in, const int* in_sizes, int n_in,
                              void* d_out, int out_size, void* d_ws, size_t ws_size,
                              hipStream_t stream) {
  const float* item = (const float*)d_in[0];
  const float* beh  = (const float*)d_in[1];
  const float* mask = (const float*)d_in[2];
  const float* Wq  = (const float*)d_in[3];  const float* bq  = (const float*)d_in[4];
  const float* Wk  = (const float*)d_in[5];  const float* bk  = (const float*)d_in[6];
  const float* Wv  = (const float*)d_in[7];  const float* bv  = (const float*)d_in[8];
  const float* Wqb = (const float*)d_in[9];  const float* bqb = (const float*)d_in[10];
  const float* Wkb = (const float*)d_in[11]; const float* bkb = (const float*)d_in[12];
  // d_in[13]/[14] = Wvb/bvb: dead code in the reference
  const float* Wf  = (const float*)d_in[15]; const float* bfv = (const float*)d_in[16];
  const float* lnw = (const float*)d_in[17]; const float* lnb = (const float*)d_in[18];
  float* out = (float*)d_out;

  ushort_t* ws = (ushort_t*)d_ws;
  ushort_t* Qw   = ws;
  ushort_t* Kw   = Qw + NE;
  ushort_t* Qbw  = Kw + NE;
  ushort_t* Kbw  = Qbw + NE;
  ushort_t* Vtw  = Kbw + NE;
  ushort_t* Opw  = Vtw + NE;             // 2*NE bf16 (two key-half partials)
  ushort_t* Wt   = Opw + 2 * (long)NE;   // 6 * H*H bf16
  float* Mpw = (float*)(Wt + 6 * H * H); // 2*NML f32
  float* Lpw = Mpw + 2 * (long)NML;      // 2*NML f32
  unsigned* mflag = (unsigned*)(Lpw + 2 * (long)NML);

  wcvt_kernel<<<dim3(4, 6), 256, 0, stream>>>(Wq, Wk, Wv, Wqb, Wkb, Wf, Wt, mflag);
  mscan_kernel<<<dim3(1024), 256, 0, stream>>>((const uint4*)mask, mflag);
  proj_kernel<<<dim3((B * S) / 32, 5), 256, 0, stream>>>(
      item, beh, Wt, bq, bk, bv, bqb, bkb, Qw, Kw, Qbw, Kbw, Vtw);
  attn_z_kernel<<<dim3((S / QT) * B * 2), 256, 0, stream>>>(
      Qw, Kw, Qbw, Kbw, Vtw, mflag, Opw, Mpw, Lpw);
  attn_m_kernel<<<dim3(S / 32, B, 2), 256, 0, stream>>>(
      Qw, Kw, Qbw, Kbw, Vtw, mask, mflag, Opw, Mpw, Lpw);
  out_kernel<<<dim3((B * S) / 16), 256, 0, stream>>>(
      Opw, Mpw, Lpw, item, Wt + 5 * H * H, bfv, lnw, lnb, out);
}

// Round 13
// 322.352 us; speedup vs baseline: 1.2102x; 1.2102x over previous
//
#include <hip/hip_runtime.h>
#include <math.h>

typedef unsigned short ushort_t;
typedef __attribute__((ext_vector_type(8))) short bf16x8;
typedef __attribute__((ext_vector_type(4))) float f32x4;

namespace {
constexpr int B = 8, S = 2048, H = 128, NH = 4, HS = 32;
constexpr float EPS = 1e-8f;
constexpr float SCALE = 0.17677669529663687f;  // 1/sqrt(32)
constexpr int QT = 16, KT = 64;
constexpr int NE = B * S * H;  // 2,097,152 elements per tensor
constexpr int NML = B * NH * S;  // per-half (m,l) rows
}

__device__ __forceinline__ ushort_t f2bf(float f) {
  unsigned u = __float_as_uint(f);
  unsigned r = (u + 0x7FFFu + ((u >> 16) & 1u)) >> 16;  // RNE
  return (ushort_t)r;
}

__device__ __forceinline__ float bf2f(ushort_t u) {
  return __uint_as_float((unsigned)u << 16);
}

__device__ __forceinline__ f32x4 mfma16(bf16x8 a, bf16x8 b, f32x4 c) {
  return __builtin_amdgcn_mfma_f32_16x16x32_bf16(a, b, c, 0, 0, 0);
}

// ---------- Kernel 0: transpose+convert weights to bf16 Wt[n][k]; SCALE folded into Wq/Wqb ----
__global__ __launch_bounds__(256) void wcvt_kernel(
    const float* __restrict__ Wq, const float* __restrict__ Wk, const float* __restrict__ Wv,
    const float* __restrict__ Wqb, const float* __restrict__ Wkb, const float* __restrict__ Wf,
    ushort_t* __restrict__ Wt)
{
  const float* Ws[6] = {Wq, Wk, Wv, Wqb, Wkb, Wf};
  const float scl[6] = {SCALE, 1.f, 1.f, SCALE, 1.f, 1.f};
  const int m = blockIdx.y;
  const int kb = blockIdx.x;           // 32-row slab of k
  const float* W = Ws[m];
  const float sc = scl[m];
  __shared__ float T[32 * 132];
  const int t = threadIdx.x;
#pragma unroll
  for (int u = 0; u < 4; ++u) {        // 32 rows x 32 float4
    const int idx = u * 256 + t;
    const int row = idx >> 5, c4 = idx & 31;
    const float4 v = *(const float4*)&W[(kb * 32 + row) * H + c4 * 4];
    *(float4*)&T[row * 132 + c4 * 4] = v;
  }
  __syncthreads();
#pragma unroll
  for (int u = 0; u < 16; ++u) {       // 128 n x 32 kk
    const int idx = u * 256 + t;
    const int n = idx >> 5, kk = idx & 31;
    Wt[m * (H * H) + n * H + kb * 32 + kk] = f2bf(T[kk * 132 + n] * sc);
  }
}

// ---------- Kernel 1: 5 projections via MFMA; blockIdx.y = projection ----------
// Q,K,Qb,Kb: [B][NH][S][HS] bf16 (Q/Qb pre-scaled) ; V: transposed [B][NH][HS][S] bf16
__global__ __launch_bounds__(256) void proj_kernel(
    const float* __restrict__ item, const float* __restrict__ beh,
    const ushort_t* __restrict__ Wt,
    const float* __restrict__ bq, const float* __restrict__ bk, const float* __restrict__ bv,
    const float* __restrict__ bqb, const float* __restrict__ bkb,
    ushort_t* __restrict__ Qo, ushort_t* __restrict__ Ko, ushort_t* __restrict__ Qbo,
    ushort_t* __restrict__ Kbo, ushort_t* __restrict__ Vto)
{
  __shared__ ushort_t Xs[32 * 136];
  __shared__ ushort_t Yb[32 * 136];
  const int t = threadIdx.x;
  const int p = blockIdx.y;
  const long r0 = (long)blockIdx.x * 32;
  const float* X = (p < 3) ? item : beh;
#pragma unroll
  for (int u = 0; u < 4; ++u) {        // 32 rows x 32 float4
    const int idx = u * 256 + t;
    const int row = idx >> 5, c4 = idx & 31;
    const float4 v = *(const float4*)&X[(r0 + row) * H + c4 * 4];
    unsigned long long pk = (unsigned long long)f2bf(v.x) | ((unsigned long long)f2bf(v.y) << 16)
        | ((unsigned long long)f2bf(v.z) << 32) | ((unsigned long long)f2bf(v.w) << 48);
    *(unsigned long long*)&Xs[row * 136 + c4 * 4] = pk;
  }
  __syncthreads();

  const int w = t >> 6, l = t & 63, l15 = l & 15, quad = l >> 4;
  const int bb = (int)(r0 >> 11);
  const int s0 = (int)(r0 & (S - 1));
  const float* bias[5] = {bq, bk, bv, bqb, bkb};
  const float bscale[5] = {SCALE, 1.f, 1.f, SCALE, 1.f};
  ushort_t* dsts[5] = {Qo, Ko, Vto, Qbo, Kbo};

  bf16x8 af[2][4];
#pragma unroll
  for (int mt = 0; mt < 2; ++mt)
#pragma unroll
    for (int ks = 0; ks < 4; ++ks)
      af[mt][ks] = *(const bf16x8*)&Xs[(mt * 16 + l15) * 136 + ks * 32 + quad * 8];

  f32x4 acc[2][2];
#pragma unroll
  for (int nt = 0; nt < 2; ++nt) {
    const float bcol = bias[p][w * 32 + nt * 16 + l15] * bscale[p];
#pragma unroll
    for (int mt = 0; mt < 2; ++mt)
      acc[mt][nt] = (f32x4){bcol, bcol, bcol, bcol};
  }
  const ushort_t* Wp = Wt + p * (H * H);
#pragma unroll
  for (int ks = 0; ks < 4; ++ks) {
    bf16x8 bfr[2];
#pragma unroll
    for (int nt = 0; nt < 2; ++nt)
      bfr[nt] = *(const bf16x8*)&Wp[(w * 32 + nt * 16 + l15) * H + ks * 32 + quad * 8];
#pragma unroll
    for (int mt = 0; mt < 2; ++mt)
#pragma unroll
      for (int nt = 0; nt < 2; ++nt)
        acc[mt][nt] = mfma16(af[mt][ks], bfr[nt], acc[mt][nt]);
  }
  // repack through LDS: Yb[row][col]
#pragma unroll
  for (int mt = 0; mt < 2; ++mt)
#pragma unroll
    for (int nt = 0; nt < 2; ++nt)
#pragma unroll
      for (int r = 0; r < 4; ++r)
        Yb[(mt * 16 + quad * 4 + r) * 136 + w * 32 + nt * 16 + l15] = f2bf(acc[mt][nt][r]);
  __syncthreads();
  ushort_t* dst = dsts[p];
  if (p == 2) {
    // Vt [b][h][d][s]: thread t -> d = t>>1, 16 consecutive s
    const int d = t >> 1, sh = (t & 1) * 16;
    ushort_t tmp[16];
#pragma unroll
    for (int i = 0; i < 16; ++i) tmp[i] = Yb[(sh + i) * 136 + d];
    const long gidx = ((long)(bb * NH + (d >> 5)) * HS + (d & 31)) * S + s0 + sh;
    *(uint4*)&dst[gidx] = *(const uint4*)&tmp[0];
    *(uint4*)&dst[gidx + 8] = *(const uint4*)&tmp[8];
  } else {
    // [b][h][s][d]: thread t -> row = t>>3, 16 consecutive cols
    const int row = t >> 3, cb = (t & 7) * 16;
    const int h = cb >> 5, dd = cb & 31;
    const long gidx = ((long)(bb * NH + h) * S + s0 + row) * HS + dd;
    *(uint4*)&dst[gidx] = *(const uint4*)&Yb[row * 136 + cb];
    *(uint4*)&dst[gidx + 8] = *(const uint4*)&Yb[row * 136 + cb + 8];
  }
}

// ---------- Kernel 2: MFMA flash attention, DUAL-Q + split-K + mask reg-prefetch ----------
// r8 structure (best measured: dual-Q chains sharing K/Kb/V, grid split-K2, next tile's mask
// prefetched as youngest VMEM). NEW: defer-max (T13, THR=8) — the full shfl-reduced max
// update + alpha exp + lsum/O rescale runs only when some score exceeds mold+8 (wave-uniform
// __any branch; lane-local growth check has no shfl chain). First iteration always takes the
// rescale path (mold=-1e30), so initialization is exact; P is bounded by e^8, which bf16/f32
// accumulation tolerates, and the factors cancel in the final O/lsum normalization.
__global__ __launch_bounds__(256, 2) void attn_kernel(
    const ushort_t* __restrict__ Q, const ushort_t* __restrict__ K,
    const ushort_t* __restrict__ Qb, const ushort_t* __restrict__ Kb,
    const ushort_t* __restrict__ Vt, const float* __restrict__ mask,
    ushort_t* __restrict__ Op, float* __restrict__ Mp, float* __restrict__ Lp)
{
  __shared__ ushort_t Pb[NH][2][16 * 72];   // per-wave, per-chain P scratch
  const int t = threadIdx.x;
  const int w = t >> 6;                  // head
  const int l = t & 63, l15 = l & 15, quad = l >> 4, quad4 = quad * 4;
  const int q0 = blockIdx.x * 32;        // two 16-row q-tiles
  const int b = blockIdx.y;
  const int half_ = blockIdx.z;
  const long hQ = (long)(b * NH + w) * S * HS;
  const long hV = (long)(b * NH + w) * HS * S;
  const ushort_t* Kp  = K + hQ;
  const ushort_t* Kbp = Kb + hQ;
  const ushort_t* Vp  = Vt + hV;

  // persistent Q/Qb A-fragments, one pair per chain (Q pre-scaled by 1/sqrt(HS))
  bf16x8 qf[2], qbf[2];
#pragma unroll
  for (int c = 0; c < 2; ++c) {
    qf[c]  = *(const bf16x8*)&Q[hQ + (long)(q0 + c * 16 + l15) * HS + quad * 8];
    qbf[c] = *(const bf16x8*)&Qb[hQ + (long)(q0 + c * 16 + l15) * HS + quad * 8];
  }

  const float* mrow[2][4];
#pragma unroll
  for (int c = 0; c < 2; ++c)
#pragma unroll
    for (int r = 0; r < 4; ++r)
      mrow[c][r] = mask + ((long)b * S + q0 + c * 16 + quad4 + r) * S + l15;

  float mold[2][4], lsum[2][4];
  f32x4 O[2][2];
#pragma unroll
  for (int c = 0; c < 2; ++c) {
#pragma unroll
    for (int r = 0; r < 4; ++r) { mold[c][r] = -1e30f; lsum[c][r] = 0.f; }
#pragma unroll
    for (int dt = 0; dt < 2; ++dt) O[c][dt] = (f32x4){0.f, 0.f, 0.f, 0.f};
  }

  const int kt0 = half_ * (S / KT / 2), kt1 = kt0 + (S / KT / 2);

  // mask ping-pong buffers; prologue fills scA for tile kt0
  f32x4 scA[2][4], scB[2][4];
#pragma unroll
  for (int c = 0; c < 2; ++c)
#pragma unroll
    for (int nt = 0; nt < 4; ++nt)
#pragma unroll
      for (int r = 0; r < 4; ++r)
        scA[c][nt][r] = mrow[c][r][kt0 * KT + nt * 16];

  auto body = [&](f32x4 (&sc)[2][4], f32x4 (&scn)[2][4], int k0, int k0n, bool pre) {
    // shared K/Kb fragment loads (oldest VMEM: QK^T waits only on these)
    bf16x8 kf[4], kbf[4];
#pragma unroll
    for (int nt = 0; nt < 4; ++nt) {
      kf[nt]  = *(const bf16x8*)&Kp[(long)(k0 + nt * 16 + l15) * HS + quad * 8];
      kbf[nt] = *(const bf16x8*)&Kbp[(long)(k0 + nt * 16 + l15) * HS + quad * 8];
    }
    // shared V fragments (consumed at PV)
    bf16x8 vf[2][2];
#pragma unroll
    for (int dt = 0; dt < 2; ++dt)
#pragma unroll
      for (int ks = 0; ks < 2; ++ks)
        vf[dt][ks] = *(const bf16x8*)&Vp[(long)(dt * 16 + l15) * S + k0 + ks * 32 + quad * 8];
    // prefetch next tile's mask (youngest VMEM: in flight across softmax+PV,
    // consumed by NEXT iteration's first MFMA)
    if (pre) {
#pragma unroll
      for (int c = 0; c < 2; ++c)
#pragma unroll
        for (int nt = 0; nt < 4; ++nt)
#pragma unroll
          for (int r = 0; r < 4; ++r)
            scn[c][nt][r] = mrow[c][r][k0n + nt * 16];
    }
    // QK^T for both chains (sc pre-initialized with mask)
#pragma unroll
    for (int c = 0; c < 2; ++c)
#pragma unroll
      for (int nt = 0; nt < 4; ++nt) {
        sc[c][nt] = mfma16(qbf[c], kbf[nt], sc[c][nt]);
        sc[c][nt] = mfma16(qf[c], kf[nt], sc[c][nt]);
      }
    // defer-max (T13): lane-local growth check, no shfl chain in the common path
    bool grow = false;
#pragma unroll
    for (int c = 0; c < 2; ++c)
#pragma unroll
      for (int r = 0; r < 4; ++r) {
        const float gm = fmaxf(fmaxf(sc[c][0][r], sc[c][1][r]),
                               fmaxf(sc[c][2][r], sc[c][3][r]));
        grow = grow || (gm > mold[c][r] + 8.f);
      }
    if (__any(grow)) {
      // rare path: full shfl-reduced max update + rescale
#pragma unroll
      for (int c = 0; c < 2; ++c) {
        float alpha[4];
#pragma unroll
        for (int r = 0; r < 4; ++r) {
          float rm = fmaxf(fmaxf(sc[c][0][r], sc[c][1][r]),
                           fmaxf(sc[c][2][r], sc[c][3][r]));
          rm = fmaxf(rm, __shfl_xor(rm, 1));
          rm = fmaxf(rm, __shfl_xor(rm, 2));
          rm = fmaxf(rm, __shfl_xor(rm, 4));
          rm = fmaxf(rm, __shfl_xor(rm, 8));
          const float mnew = fmaxf(mold[c][r], rm);
          alpha[r] = __expf(mold[c][r] - mnew);
          lsum[c][r] *= alpha[r];
          mold[c][r] = mnew;
        }
#pragma unroll
        for (int dt = 0; dt < 2; ++dt)
#pragma unroll
          for (int r = 0; r < 4; ++r)
            O[c][dt][r] *= alpha[r];
      }
    }
    // P = exp(sc - mold) (bounded by e^8), accumulate lsum; write P to LDS
#pragma unroll
    for (int c = 0; c < 2; ++c) {
#pragma unroll
      for (int r = 0; r < 4; ++r) {
        float rs = 0.f;
#pragma unroll
        for (int nt = 0; nt < 4; ++nt) {
          const float p = __expf(sc[c][nt][r] - mold[c][r]);
          sc[c][nt][r] = p;
          rs += p;
        }
        rs += __shfl_xor(rs, 1);
        rs += __shfl_xor(rs, 2);
        rs += __shfl_xor(rs, 4);
        rs += __shfl_xor(rs, 8);
        lsum[c][r] += rs;
      }
      ushort_t* Pw = Pb[w][c];
#pragma unroll
      for (int nt = 0; nt < 4; ++nt)
#pragma unroll
        for (int r = 0; r < 4; ++r)
          Pw[(quad4 + r) * 72 + nt * 16 + l15] = f2bf(sc[c][nt][r]);
    }
    // PV for both chains (intra-wave LDS dependency only)
#pragma unroll
    for (int c = 0; c < 2; ++c) {
      const ushort_t* Pw = Pb[w][c];
      bf16x8 pf[2];
#pragma unroll
      for (int ks = 0; ks < 2; ++ks)
        pf[ks] = *(const bf16x8*)&Pw[l15 * 72 + ks * 32 + quad * 8];
#pragma unroll
      for (int dt = 0; dt < 2; ++dt)
#pragma unroll
        for (int ks = 0; ks < 2; ++ks)
          O[c][dt] = mfma16(pf[ks], vf[dt][ks], O[c][dt]);
    }
  };

  for (int kt = kt0; kt < kt1; kt += 2) {
    body(scA, scB, kt * KT, (kt + 1) * KT, true);
    body(scB, scA, (kt + 1) * KT, (kt + 2) * KT, kt + 2 < kt1);
  }

  // epilogue: normalized bf16 partial O + (m,l) per row, per chain
#pragma unroll
  for (int c = 0; c < 2; ++c) {
#pragma unroll
    for (int r = 0; r < 4; ++r) {
      const float inv = 1.f / lsum[c][r];
      const long row = (long)b * S + q0 + c * 16 + quad4 + r;
#pragma unroll
      for (int dt = 0; dt < 2; ++dt)
        Op[(long)half_ * NE + row * H + w * 32 + dt * 16 + l15] = f2bf(O[c][dt][r] * inv);
    }
    if (l15 == 0) {
#pragma unroll
      for (int r = 0; r < 4; ++r) {
        const long idx = ((long)(half_ * B + b) * NH + w) * S + q0 + c * 16 + quad4 + r;
        Mp[idx] = mold[c][r];
        Lp[idx] = lsum[c][r];
      }
    }
  }
}

// ---------- Kernel 3: merge split-K halves + attn @ Wf + bias + residual + LayerNorm ----------
__global__ __launch_bounds__(256) void out_kernel(
    const ushort_t* __restrict__ Op, const float* __restrict__ Mp, const float* __restrict__ Lp,
    const float* __restrict__ item,
    const ushort_t* __restrict__ Wft, const float* __restrict__ bf_,
    const float* __restrict__ lnw, const float* __restrict__ lnb,
    float* __restrict__ out)
{
  __shared__ ushort_t As[16 * 136];
  __shared__ float Ys[16 * 132];
  const int t = threadIdx.x;
  const long r0 = (long)blockIdx.x * 16;
  {
    // merge halves: 16 rows x 16 chunks of 8 bf16
    const int row = t >> 4, c8 = t & 15;
    const long g = r0 + row;
    const int bb = (int)(g >> 11);
    const int ss = (int)(g & (S - 1));
    const int col0 = c8 * 8;
    const int h = col0 >> 5;
    const long mlidx = ((long)bb * NH + h) * S + ss;
    const float m1 = Mp[mlidx], m2 = Mp[(long)NML + mlidx];
    const float l1 = Lp[mlidx], l2 = Lp[(long)NML + mlidx];
    const float M = fmaxf(m1, m2);
    const float w1 = l1 * __expf(m1 - M), w2 = l2 * __expf(m2 - M);
    const float inv = 1.f / (w1 + w2);
    const float wa = w1 * inv, wb = w2 * inv;
    const uint4 a1 = *(const uint4*)&Op[g * H + col0];
    const uint4 a2 = *(const uint4*)&Op[(long)NE + g * H + col0];
    const ushort_t* p1 = (const ushort_t*)&a1;
    const ushort_t* p2 = (const ushort_t*)&a2;
    ushort_t mg[8];
#pragma unroll
    for (int i = 0; i < 8; ++i)
      mg[i] = f2bf(bf2f(p1[i]) * wa + bf2f(p2[i]) * wb);
    *(uint4*)&As[row * 136 + col0] = *(const uint4*)&mg[0];
  }
  __syncthreads();
  const int w = t >> 6, l = t & 63, l15 = l & 15, quad = l >> 4;
  f32x4 acc[2];
#pragma unroll
  for (int nt = 0; nt < 2; ++nt) {
    const float bcol = bf_[w * 32 + nt * 16 + l15];
    acc[nt] = (f32x4){bcol, bcol, bcol, bcol};
  }
#pragma unroll
  for (int ks = 0; ks < 4; ++ks) {
    const bf16x8 a = *(const bf16x8*)&As[l15 * 136 + ks * 32 + quad * 8];
#pragma unroll
    for (int nt = 0; nt < 2; ++nt) {
      const bf16x8 bfr = *(const bf16x8*)&Wft[(w * 32 + nt * 16 + l15) * H + ks * 32 + quad * 8];
      acc[nt] = mfma16(a, bfr, acc[nt]);
    }
  }
  // Y = acc + item -> LDS
#pragma unroll
  for (int nt = 0; nt < 2; ++nt)
#pragma unroll
    for (int r = 0; r < 4; ++r) {
      const int rl = quad * 4 + r;
      const int col = w * 32 + nt * 16 + l15;
      Ys[rl * 132 + col] = acc[nt][r] + item[(r0 + rl) * H + col];
    }
  __syncthreads();
  // LayerNorm: 16 threads per row, 8 cols each
  const int rl = t >> 4, ch = t & 15;
  float v[8];
#pragma unroll
  for (int g = 0; g < 2; ++g) {
    const float4 y = *(const float4*)&Ys[rl * 132 + ch * 8 + g * 4];
    v[g * 4 + 0] = y.x; v[g * 4 + 1] = y.y; v[g * 4 + 2] = y.z; v[g * 4 + 3] = y.w;
  }
  float s = 0.f;
#pragma unroll
  for (int i = 0; i < 8; ++i) s += v[i];
  s += __shfl_xor(s, 1);
  s += __shfl_xor(s, 2);
  s += __shfl_xor(s, 4);
  s += __shfl_xor(s, 8);
  const float u_ = s * (1.f / H);
  float s2 = 0.f;
#pragma unroll
  for (int i = 0; i < 8; ++i) { const float d = v[i] - u_; s2 += d * d; }
  s2 += __shfl_xor(s2, 1);
  s2 += __shfl_xor(s2, 2);
  s2 += __shfl_xor(s2, 4);
  s2 += __shfl_xor(s2, 8);
  const float rinv = rsqrtf(s2 * (1.f / H) + EPS);
#pragma unroll
  for (int g = 0; g < 2; ++g) {
    float4 o;
    const int col = ch * 8 + g * 4;
    o.x = lnw[col + 0] * ((v[g * 4 + 0] - u_) * rinv) + lnb[col + 0];
    o.y = lnw[col + 1] * ((v[g * 4 + 1] - u_) * rinv) + lnb[col + 1];
    o.z = lnw[col + 2] * ((v[g * 4 + 2] - u_) * rinv) + lnb[col + 2];
    o.w = lnw[col + 3] * ((v[g * 4 + 3] - u_) * rinv) + lnb[col + 3];
    *(float4*)&out[(r0 + rl) * H + col] = o;
  }
}

extern "C" void kernel_launch(void* const* d_in, const int* in_sizes, int n_in,
                              void* d_out, int out_size, void* d_ws, size_t ws_size,
                              hipStream_t stream) {
  const float* item = (const float*)d_in[0];
  const float* beh  = (const float*)d_in[1];
  const float* mask = (const float*)d_in[2];
  const float* Wq  = (const float*)d_in[3];  const float* bq  = (const float*)d_in[4];
  const float* Wk  = (const float*)d_in[5];  const float* bk  = (const float*)d_in[6];
  const float* Wv  = (const float*)d_in[7];  const float* bv  = (const float*)d_in[8];
  const float* Wqb = (const float*)d_in[9];  const float* bqb = (const float*)d_in[10];
  const float* Wkb = (const float*)d_in[11]; const float* bkb = (const float*)d_in[12];
  // d_in[13]/[14] = Wvb/bvb: dead code in the reference
  const float* Wf  = (const float*)d_in[15]; const float* bfv = (const float*)d_in[16];
  const float* lnw = (const float*)d_in[17]; const float* lnb = (const float*)d_in[18];
  float* out = (float*)d_out;

  ushort_t* ws = (ushort_t*)d_ws;
  ushort_t* Qw   = ws;
  ushort_t* Kw   = Qw + NE;
  ushort_t* Qbw  = Kw + NE;
  ushort_t* Kbw  = Qbw + NE;
  ushort_t* Vtw  = Kbw + NE;
  ushort_t* Opw  = Vtw + NE;             // 2*NE bf16 (two key-half partials)
  ushort_t* Wt   = Opw + 2 * (long)NE;   // 6 * H*H bf16
  float* Mpw = (float*)(Wt + 6 * H * H); // 2*NML f32
  float* Lpw = Mpw + 2 * (long)NML;      // 2*NML f32

  wcvt_kernel<<<dim3(4, 6), 256, 0, stream>>>(Wq, Wk, Wv, Wqb, Wkb, Wf, Wt);
  proj_kernel<<<dim3((B * S) / 32, 5), 256, 0, stream>>>(
      item, beh, Wt, bq, bk, bv, bqb, bkb, Qw, Kw, Qbw, Kbw, Vtw);
  attn_kernel<<<dim3(S / 32, B, 2), 256, 0, stream>>>(
      Qw, Kw, Qbw, Kbw, Vtw, mask, Opw, Mpw, Lpw);
  out_kernel<<<dim3((B * S) / 16), 256, 0, stream>>>(
      Opw, Mpw, Lpw, item, Wt + 5 * H * H, bfv, lnw, lnb, out);
}